// Round 17
// baseline (258.638 us; speedup 1.0000x reference)
//
#include <hip/hip_runtime.h>
#include <hip/hip_bf16.h>

typedef __attribute__((ext_vector_type(8))) short bf16x8;
typedef __attribute__((ext_vector_type(4))) float f32x4;
typedef unsigned short ush;

constexpr int NODESV = 340, CIN = 18;
constexpr int GRP = 20;     // padded group stride (17 valid + 3 pad)
constexpr int NSLOT = 400;  // 20 groups * 20
constexpr int NTILE = 25;   // 400/16
constexpr int RS1 = 412;    // z1g row stride (16-bank spread, covers quad3 overread)
constexpr int SLX = 3208;   // xsb slice stride
constexpr int SL8 = 3200;   // z2s slice stride
constexpr int PC = 6120;    // 340*18
constexpr int PCP = 6144;   // padded xT row (ush); bf16 outS row (5440) overlays it
constexpr int QN = 5440;    // 340*16

// d_ws layout (bytes)
constexpr int    WS_SB_F  = 21 * 16;                     // SbA float offset after bgvA
constexpr int    WS_WG    = 1536;
constexpr int    WS_WT    = WS_WG + 21 * 64 * 8 * 2;     // 23040
constexpr int    WS_ASP   = WS_WT + 21 * 64 * 8 * 2;     // 44544: Asp frags [4][64][8] bf16
constexpr int    WS_R16   = WS_ASP + 4096;               // 48640: row-16 [4][32] bf16
constexpr size_t WS_XT    = 65536;
constexpr size_t WS_NEED  = WS_XT + (size_t)8 * 256 * PCP * 2;   // 25,231,360

__device__ __forceinline__ ush f2bf(float f) {
    union { __hip_bfloat16 h; ush u; } c; c.h = __float2bfloat16(f); return c.u;
}
__device__ __forceinline__ float bf2f(ush s) {
    return __uint_as_float((unsigned)s << 16);
}
__device__ __forceinline__ unsigned pkbf2(float lo, float hi) {
    union { __hip_bfloat162 h; unsigned u; } c;
    c.h = __float22bfloat162_rn(make_float2(lo, hi));
    return c.u;
}

// ---------------- prep: fold BN into bf16 weight frags + Asp frags, once ----------------
__global__ void stgcn_prep(
    const float* __restrict__ Asp,
    const float* __restrict__ Wg0, const float* __restrict__ bg0,
    const float* __restrict__ Wgx, const float* __restrict__ bgx,
    const float* __restrict__ g1,  const float* __restrict__ b1,
    const float* __restrict__ Wt,  const float* __restrict__ bt,
    const float* __restrict__ g2,  const float* __restrict__ b2,
    void* __restrict__ ws)
{
    const int lk = blockIdx.x;            // 0..20
    const int l = lk / 7, k = lk % 7;
    const int lane = threadIdx.x;         // 0..63
    const int o = lane & 15, quad = lane >> 4;
    float* bgvA = (float*)ws;
    float* SbA  = bgvA + WS_SB_F;
    ush* wgF = (ush*)((char*)ws + WS_WG);
    ush* wtF = (ush*)((char*)ws + WS_WT);
    const float rs = 1.0f / sqrtf(1.0f + 1e-5f);
    const float s1 = g1[lk * 16 + o] * rs;
    const float s2 = g2[lk * 16 + o] * rs;

    unsigned wg4[4], wt4[4];
    #pragma unroll
    for (int i2 = 0; i2 < 4; ++i2) {
        int c0 = quad * 8 + i2 * 2, c1 = c0 + 1;
        float a0, a1;
        if (l == 0) {
            a0 = (c0 < 18) ? Wg0[(k * 16 + o) * 18 + c0] * s1 : 0.f;
            a1 = (c1 < 18) ? Wg0[(k * 16 + o) * 18 + c1] * s1 : 0.f;
        } else {
            a0 = (c0 < 16) ? Wgx[(((l - 1) * 7 + k) * 16 + o) * 16 + c0] * s1 : 0.f;
            a1 = (c1 < 16) ? Wgx[(((l - 1) * 7 + k) * 16 + o) * 16 + c1] * s1 : 0.f;
        }
        float t0 = (c0 < 16) ? Wt[(lk * 16 + o) * 16 + c0] * s2 : 0.f;
        float t1 = (c1 < 16) ? Wt[(lk * 16 + o) * 16 + c1] * s2 : 0.f;
        wg4[i2] = pkbf2(a0, a1);
        wt4[i2] = pkbf2(t0, t1);
    }
    *(uint4*)&wgF[(lk * 64 + lane) * 8] = make_uint4(wg4[0], wg4[1], wg4[2], wg4[3]);
    *(uint4*)&wtF[(lk * 64 + lane) * 8] = make_uint4(wt4[0], wt4[1], wt4[2], wt4[3]);
    if (quad == 0)
        bgvA[lk * 16 + o] = ((l == 0) ? bg0[k * 16 + o] : bgx[((l - 1) * 7 + k) * 16 + o]) * s1;
    if (lk == 0 && lane < 48) {
        int ll = lane >> 4, ch = lane & 15;
        float s = 0.f;
        for (int kk = 0; kk < 7; ++kk) {
            int q = (ll * 7 + kk) * 16 + ch;
            s += bt[q] * (g2[q] * rs) + b2[q];
        }
        SbA[ll * 16 + ch] = s;
    }
    if (lk < 4) {   // Asp MFMA frags + row16 -> ws
        ush* aspF = (ush*)((char*)ws + WS_ASP);
        ush* r16F = (ush*)((char*)ws + WS_R16);
        bf16x8 a0 = {};
        #pragma unroll
        for (int i = 0; i < 8; ++i) {
            int v = quad * 8 + i;
            a0[i] = (short)((v < 17) ? f2bf(Asp[(lk * 17 + o) * 17 + v]) : 0);
        }
        *(bf16x8*)&aspF[(lk * 64 + lane) * 8] = a0;
        if (lane < 32)
            r16F[lk * 32 + lane] = (lane < 17) ? f2bf(Asp[(lk * 17 + 16) * 17 + lane]) : (ush)0;
    }
}

// ---------------- transpose-in: x (n,pc,hw) f32 -> xT[site][pc] bf16 ----------------
__global__ __launch_bounds__(256) void stgcn_tin(const float* __restrict__ x,
                                                 void* __restrict__ ws)
{
    __shared__ float tf[32][256];
    const int b = blockIdx.x, tid = threadIdx.x;
    const int n = b & 7, pc0 = (b >> 3) * 32;
    for (int j = 0; j < 32; ++j) {
        int pc = pc0 + j;
        tf[j][tid] = (pc < PC) ? x[((size_t)n * PC + pc) * 256 + tid] : 0.f;
    }
    __syncthreads();
    ush* dst = (ush*)((char*)ws + WS_XT) + (size_t)(n * 256 + tid) * PCP + pc0;
    unsigned pk[16];
    #pragma unroll
    for (int j2 = 0; j2 < 16; ++j2) pk[j2] = pkbf2(tf[2 * j2][tid], tf[2 * j2 + 1][tid]);
    #pragma unroll
    for (int q4 = 0; q4 < 4; ++q4)
        *(uint4*)&dst[q4 * 8] = make_uint4(pk[q4*4], pk[q4*4+1], pk[q4*4+2], pk[q4*4+3]);
}

// ---------------- transpose-out (bf16 outS overlaid on xT rows) ----------------
__global__ __launch_bounds__(256) void stgcn_tout_bf(const void* __restrict__ ws,
                                                     float* __restrict__ out)
{
    __shared__ ush tg[32][256];
    const int b = blockIdx.x, tid = threadIdx.x;
    const int n = b & 7, q0 = (b >> 3) * 32;
    const ush* src = (const ush*)((const char*)ws + WS_XT) + (size_t)(n * 256 + tid) * PCP + q0;
    #pragma unroll
    for (int j4 = 0; j4 < 4; ++j4) {
        uint4 v = *(const uint4*)&src[j4 * 8];
        unsigned u[4] = {v.x, v.y, v.z, v.w};
        #pragma unroll
        for (int e = 0; e < 4; ++e) {
            tg[j4*8 + e*2 + 0][tid] = (ush)(u[e] & 0xffffu);
            tg[j4*8 + e*2 + 1][tid] = (ush)(u[e] >> 16);
        }
    }
    __syncthreads();
    for (int j = 0; j < 32; ++j)
        out[((size_t)n * QN + q0 + j) * 256 + tid] = bf2f(tg[j][tid]);
}

// ---------------- main fused 3-layer kernel, one block per (n,hw) ----------------
// TP: 1 = read bf16 xT from ws and write bf16 outS over own xT row. 0 = direct global I/O.
// Register-diet version: two-pass V-mix (aA and aB never co-live) + wt loaded after
// aggregation -> peak live regs ~60 so the 64-reg/8-wave allocation is spill-free,
// while __launch_bounds__(256,4) keeps the 4-blocks/CU residency (42% occupancy, r15).
template<int TP>
__global__ __launch_bounds__(256, 4) void stgcn_main(
    const float* __restrict__ x,
    const float* __restrict__ Asp_g, const float* __restrict__ Atm_g, const float* __restrict__ Avw_g,
    const float* __restrict__ b1, void* __restrict__ ws,
    float* __restrict__ out)
{
    __shared__ __align__(16) ush xsb[2 * SLX];      // 12832 B  x channels 0-15
    __shared__ __align__(16) ush xs2[NSLOT * 2];    //  1600 B  x channels 16-17 (layer 0)
    __shared__ __align__(16) ush z1g[16 * RS1];     // 13184 B  [o][slot]
    __shared__ __align__(16) ush z2s[2 * SL8];      // 12800 B  [c>>3][slot][c&7]

    const int tid  = threadIdx.x;
    const int wv   = tid >> 6;
    const int lane = tid & 63;
    const int o    = tid & 15;
    const int quad = (tid >> 4) & 3;
    const int w16  = tid >> 4;
    const int bid  = blockIdx.x;
    const int n = bid & 7, hw = bid >> 3;   // XCD swizzle: one batch image per XCD

    const float* bgvA = (const float*)ws;
    const float* SbA  = bgvA + WS_SB_F;
    const ush* wgF  = (const ush*)((const char*)ws + WS_WG);
    const ush* wtF  = (const ush*)((const char*)ws + WS_WT);
    const ush* aspF = (const ush*)((const char*)ws + WS_ASP);
    const ush* r16F = (const ush*)((const char*)ws + WS_R16);

    // zero LDS (pads/tails must be finite-zero)
    for (int i = tid; i < SLX; i += 256) ((unsigned*)xsb)[i] = 0u;
    for (int i = tid; i < NSLOT; i += 256) ((unsigned*)xs2)[i] = 0u;
    for (int i = tid; i < (16 * RS1) / 2; i += 256) ((unsigned*)z1g)[i] = 0u;
    for (int i = tid; i < SL8; i += 256) ((unsigned*)z2s)[i] = 0u;
    __syncthreads();

    // load x -> bf16 LDS (slot-padded subtiled layout; ch 16-17 compact)
    if (TP) {
        const ush* xrow = (const ush*)((const char*)ws + WS_XT) + (size_t)(n * 256 + hw) * PCP;
        for (int i = tid; i < PC; i += 256) {
            int p = i / CIN, c = i - p * CIN;
            int slot = p + 3 * (p / 17);
            if (c < 16) xsb[(c >> 3) * SLX + slot * 8 + (c & 7)] = xrow[i];
            else        xs2[slot * 2 + (c - 16)] = xrow[i];
        }
    } else {
        const float* xb = x + (size_t)n * PC * 256 + hw;
        for (int i = tid; i < PC; i += 256) {
            int p = i / CIN, c = i - p * CIN;
            int slot = p + 3 * (p / 17);
            ush v = f2bf(xb[(size_t)i * 256]);
            if (c < 16) xsb[(c >> 3) * SLX + slot * 8 + (c & 7)] = v;
            else        xs2[slot * 2 + (c - 16)] = v;
        }
    }
    __syncthreads();

    f32x4 acc[7];

    #pragma unroll 1
    for (int l = 0; l < 3; ++l) {
        // init acc: residual = 7*x (re-read bf16 from xsb; branches see the same values)
        #pragma unroll
        for (int t = 0; t < 7; ++t) {
            int tile = t * 4 + wv;
            f32x4 z = {0.f, 0.f, 0.f, 0.f};
            acc[t] = z;
            if (l > 0 && tile < NTILE) {
                int node = tile * 16 + o;
                uint2 w = *(const uint2*)&xsb[(quad >> 1) * SLX + node * 8 + (quad & 1) * 4];
                acc[t][0] = 7.f * bf2f((ush)(w.x & 0xffffu));
                acc[t][1] = 7.f * bf2f((ush)(w.x >> 16));
                acc[t][2] = 7.f * bf2f((ush)(w.y & 0xffffu));
                acc[t][3] = 7.f * bf2f((ush)(w.y >> 16));
            }
        }

        #pragma unroll 1   // rolled: small body, low register pressure
        for (int k = 0; k < 7; ++k) {
            const int lk = l * 7 + k;
            bf16x8 wg = *(const bf16x8*)&wgF[(lk * 64 + lane) * 8];
            const float bgv = bgvA[lk * 16 + o];

            // ---- conv1: z1[o][slot] via MFMA (bias in C-operand) ----
            // quads 0,1 carry ch 0-15; quad 2 only layer-0 ch 16,17; quad 3 zero.
            #pragma unroll
            for (int t = 0; t < 7; ++t) {
                int tile = t * 4 + wv;
                if (tile < NTILE) {
                    int node = tile * 16 + o;
                    bf16x8 xa = {};
                    if (quad < 2) {
                        xa = *(const bf16x8*)&xsb[quad * SLX + node * 8];
                    } else if (quad == 2 && l == 0) {
                        unsigned w2 = *(const unsigned*)&xs2[node * 2];
                        xa[0] = (short)(ush)(w2 & 0xffffu);
                        xa[1] = (short)(ush)(w2 >> 16);
                    }
                    f32x4 z = {bgv, bgv, bgv, bgv};
                    z = __builtin_amdgcn_mfma_f32_16x16x32_bf16(xa, wg, z, 0, 0, 0);
                    *(uint2*)&z1g[o * RS1 + tile * 16 + quad * 4] =
                        make_uint2(pkbf2(z[0], z[1]), pkbf2(z[2], z[3]));
                }
            }
            __syncthreads();

            // ---- aggregation -> z2s [c>>3][slot][c&7] ----
            if (k < 4) {   // V-mix, transposed MFMA, TWO PASSES (aA / aB never co-live)
                float4 b1q = *(const float4*)&b1[lk * 16 + quad * 4];
                {   // pass 1: rows u=0..15 of every group
                    bf16x8 aA = *(const bf16x8*)&aspF[(k * 64 + lane) * 8];
                    #pragma unroll
                    for (int gi = 0; gi < 5; ++gi) {
                        int grp = gi * 4 + wv;   // 0..19
                        bf16x8 bz = *(const bf16x8*)&z1g[o * RS1 + grp * GRP + quad * 8];
                        f32x4 y0 = {b1q.x, b1q.y, b1q.z, b1q.w};
                        y0 = __builtin_amdgcn_mfma_f32_16x16x32_bf16(bz, aA, y0, 0, 0, 0);
                        *(uint2*)&z2s[(quad >> 1) * SL8 + (grp * GRP + o) * 8 + (quad & 1) * 4] =
                            make_uint2(pkbf2(fmaxf(y0[0], 0.f), fmaxf(y0[1], 0.f)),
                                       pkbf2(fmaxf(y0[2], 0.f), fmaxf(y0[3], 0.f)));
                    }
                }
                {   // pass 2: row u=16 (result used by o==0 lanes only); bz re-read
                    bf16x8 aB = {};
                    if (o == 0) aB = *(const bf16x8*)&r16F[k * 32 + quad * 8];
                    #pragma unroll
                    for (int gi = 0; gi < 5; ++gi) {
                        int grp = gi * 4 + wv;
                        bf16x8 bz = *(const bf16x8*)&z1g[o * RS1 + grp * GRP + quad * 8];
                        f32x4 y1 = {b1q.x, b1q.y, b1q.z, b1q.w};
                        y1 = __builtin_amdgcn_mfma_f32_16x16x32_bf16(bz, aB, y1, 0, 0, 0);
                        if (o == 0) {
                            *(uint2*)&z2s[(quad >> 1) * SL8 + (grp * GRP + 16) * 8 + (quad & 1) * 4] =
                                make_uint2(pkbf2(fmaxf(y1[0], 0.f), fmaxf(y1[1], 0.f)),
                                           pkbf2(fmaxf(y1[2], 0.f), fmaxf(y1[3], 0.f)));
                        }
                    }
                }
            } else if (k < 6) {   // T-mix (K=5), per-group VALU
                const float b1v = b1[lk * 16 + o];
                const float* Ar = Atm_g + (k - 4) * 25;
                #pragma unroll
                for (int j = 0; j < 5; ++j) {
                    int g = w16 + 16 * j;
                    if (g < 68) {
                        int vw = g / 17, v = g - vw * 17;
                        float vals[5];
                        #pragma unroll
                        for (int t2 = 0; t2 < 5; ++t2)
                            vals[t2] = bf2f(z1g[o * RS1 + vw * 100 + t2 * GRP + v]);
                        #pragma unroll
                        for (int tp = 0; tp < 5; ++tp) {
                            float y = b1v;
                            #pragma unroll
                            for (int t2 = 0; t2 < 5; ++t2)
                                y = fmaf(Ar[tp * 5 + t2], vals[t2], y);
                            z2s[(o >> 3) * SL8 + ((vw * 5 + tp) * GRP + v) * 8 + (o & 7)] =
                                f2bf(fmaxf(y, 0.f));
                        }
                    }
                }
            } else {   // View-mix (K=4), per-group VALU
                const float b1v = b1[lk * 16 + o];
                #pragma unroll
                for (int j = 0; j < 6; ++j) {
                    int g = w16 + 16 * j;
                    if (g < 85) {
                        int tt = g / 17, v = g - tt * 17;
                        float vals[4];
                        #pragma unroll
                        for (int vw = 0; vw < 4; ++vw)
                            vals[vw] = bf2f(z1g[o * RS1 + vw * 100 + tt * GRP + v]);
                        #pragma unroll
                        for (int vp = 0; vp < 4; ++vp) {
                            float y = b1v;
                            #pragma unroll
                            for (int vw = 0; vw < 4; ++vw)
                                y = fmaf(Avw_g[vp * 4 + vw], vals[vw], y);
                            z2s[(o >> 3) * SL8 + ((vp * 5 + tt) * GRP + v) * 8 + (o & 7)] =
                                f2bf(fmaxf(y, 0.f));
                        }
                    }
                }
            }
            __syncthreads();

            // ---- conv2 (transposed): wt loaded HERE (not hoisted across conv1/agg) ----
            // quads 0,1 carry ch 0-15; quads 2,3 operand zero (wt already zero there).
            {
                bf16x8 wt = *(const bf16x8*)&wtF[(lk * 64 + lane) * 8];
                #pragma unroll
                for (int t = 0; t < 7; ++t) {
                    int tile = t * 4 + wv;
                    if (tile < NTILE) {
                        int node = tile * 16 + o;
                        bf16x8 za = {};
                        if (quad < 2) za = *(const bf16x8*)&z2s[quad * SL8 + node * 8];
                        acc[t] = __builtin_amdgcn_mfma_f32_16x16x32_bf16(wt, za, acc[t], 0, 0, 0);
                    }
                }
            }
            // no barrier: next conv1 writes z1g only; barrier after it orders z2s reuse
        }

        // ---- finalize layer ----
        float4 Sb4 = *(const float4*)&SbA[l * 16 + quad * 4];
        if (l < 2) {
            __syncthreads();   // all conv1 xsb reads done before overwrite
            #pragma unroll
            for (int t = 0; t < 7; ++t) {
                int tile = t * 4 + wv;
                if (tile < NTILE) {
                    float v0 = fmaxf(acc[t][0] + Sb4.x, 0.f);
                    float v1 = fmaxf(acc[t][1] + Sb4.y, 0.f);
                    float v2 = fmaxf(acc[t][2] + Sb4.z, 0.f);
                    float v3 = fmaxf(acc[t][3] + Sb4.w, 0.f);
                    int s = tile * 16 + o;
                    *(uint2*)&xsb[(quad >> 1) * SLX + s * 8 + (quad & 1) * 4] =
                        make_uint2(pkbf2(v0, v1), pkbf2(v2, v3));
                }
            }
            __syncthreads();
        } else {
            #pragma unroll
            for (int t = 0; t < 7; ++t) {
                int tile = t * 4 + wv;
                if (tile < NTILE) {
                    int s = tile * 16 + o;
                    int m = s / GRP, vv = s - GRP * m;
                    if (vv < 17) {
                        int p = m * 17 + vv;
                        float r0 = fmaxf(acc[t][0] + Sb4.x, 0.f);
                        float r1 = fmaxf(acc[t][1] + Sb4.y, 0.f);
                        float r2 = fmaxf(acc[t][2] + Sb4.z, 0.f);
                        float r3 = fmaxf(acc[t][3] + Sb4.w, 0.f);
                        if (TP) {
                            ush* osrow = (ush*)((char*)ws + WS_XT) + (size_t)(n * 256 + hw) * PCP;
                            *(uint2*)&osrow[p * 16 + quad * 4] =
                                make_uint2(pkbf2(r0, r1), pkbf2(r2, r3));
                        } else {
                            float* ob = out + ((size_t)((n * NODESV + p) * 16 + quad * 4)) * 256 + hw;
                            ob[0] = r0; ob[256] = r1; ob[512] = r2; ob[768] = r3;
                        }
                    }
                }
            }
        }
    }
}

extern "C" void kernel_launch(void* const* d_in, const int* in_sizes, int n_in,
                              void* d_out, int out_size, void* d_ws, size_t ws_size,
                              hipStream_t stream) {
    const float* x    = (const float*)d_in[0];
    const float* Asp  = (const float*)d_in[1];
    const float* Atm  = (const float*)d_in[2];
    const float* Avw  = (const float*)d_in[3];
    const float* Wg0  = (const float*)d_in[4];
    const float* bg0  = (const float*)d_in[5];
    const float* Wgx  = (const float*)d_in[6];
    const float* bgx  = (const float*)d_in[7];
    const float* g1   = (const float*)d_in[8];
    const float* b1   = (const float*)d_in[9];
    const float* Wt   = (const float*)d_in[10];
    const float* bt   = (const float*)d_in[11];
    const float* g2   = (const float*)d_in[12];
    const float* b2   = (const float*)d_in[13];
    float* out = (float*)d_out;

    stgcn_prep<<<dim3(21), dim3(64), 0, stream>>>(
        Asp, Wg0, bg0, Wgx, bgx, g1, b1, Wt, bt, g2, b2, d_ws);

    if (ws_size >= WS_NEED) {
        stgcn_tin<<<dim3(8 * 192), dim3(256), 0, stream>>>(x, d_ws);
        stgcn_main<1><<<dim3(8 * 256), dim3(256), 0, stream>>>(
            x, Asp, Atm, Avw, b1, d_ws, out);
        stgcn_tout_bf<<<dim3(8 * 170), dim3(256), 0, stream>>>(d_ws, out);
    } else {
        stgcn_main<0><<<dim3(8 * 256), dim3(256), 0, stream>>>(
            x, Asp, Atm, Avw, b1, d_ws, out);
    }
}

// Round 18
// 236.311 us; speedup vs baseline: 1.0945x; 1.0945x over previous
//
#include <hip/hip_runtime.h>
#include <hip/hip_bf16.h>

typedef __attribute__((ext_vector_type(8))) short bf16x8;
typedef __attribute__((ext_vector_type(4))) float f32x4;
typedef unsigned short ush;

constexpr int NODESV = 340, CIN = 18;
constexpr int GRP = 20;     // padded group stride (17 valid + 3 pad)
constexpr int NSLOT = 400;  // 20 groups * 20
constexpr int NTILE = 25;   // 400/16
constexpr int RS1 = 412;    // z1g row stride (16-bank spread, covers quad3 overread)
constexpr int SLX = 3208;   // xsb slice stride
constexpr int SL8 = 3200;   // z2s slice stride
constexpr int PC = 6120;    // 340*18
constexpr int PCP = 6144;   // padded xT row (ush); bf16 outS row (5440) overlays it
constexpr int QN = 5440;    // 340*16

// d_ws layout (bytes)
constexpr int    WS_SB_F  = 21 * 16;                     // SbA float offset after bgvA
constexpr int    WS_WG    = 1536;
constexpr int    WS_WT    = WS_WG + 21 * 64 * 8 * 2;     // 23040
constexpr int    WS_ASP   = WS_WT + 21 * 64 * 8 * 2;     // 44544: Asp frags [4][64][8] bf16
constexpr int    WS_R16   = WS_ASP + 4096;               // 48640: row-16 [4][32] bf16
constexpr size_t WS_XT    = 65536;
constexpr size_t WS_NEED  = WS_XT + (size_t)8 * 256 * PCP * 2;   // 25,231,360

__device__ __forceinline__ ush f2bf(float f) {
    union { __hip_bfloat16 h; ush u; } c; c.h = __float2bfloat16(f); return c.u;
}
__device__ __forceinline__ float bf2f(ush s) {
    return __uint_as_float((unsigned)s << 16);
}
__device__ __forceinline__ unsigned pkbf2(float lo, float hi) {
    union { __hip_bfloat162 h; unsigned u; } c;
    c.h = __float22bfloat162_rn(make_float2(lo, hi));
    return c.u;
}

// ---------------- prep: fold BN into bf16 weight frags + Asp frags, once ----------------
__global__ void stgcn_prep(
    const float* __restrict__ Asp,
    const float* __restrict__ Wg0, const float* __restrict__ bg0,
    const float* __restrict__ Wgx, const float* __restrict__ bgx,
    const float* __restrict__ g1,  const float* __restrict__ b1,
    const float* __restrict__ Wt,  const float* __restrict__ bt,
    const float* __restrict__ g2,  const float* __restrict__ b2,
    void* __restrict__ ws)
{
    const int lk = blockIdx.x;            // 0..20
    const int l = lk / 7, k = lk % 7;
    const int lane = threadIdx.x;         // 0..63
    const int o = lane & 15, quad = lane >> 4;
    float* bgvA = (float*)ws;
    float* SbA  = bgvA + WS_SB_F;
    ush* wgF = (ush*)((char*)ws + WS_WG);
    ush* wtF = (ush*)((char*)ws + WS_WT);
    const float rs = 1.0f / sqrtf(1.0f + 1e-5f);
    const float s1 = g1[lk * 16 + o] * rs;
    const float s2 = g2[lk * 16 + o] * rs;

    unsigned wg4[4], wt4[4];
    #pragma unroll
    for (int i2 = 0; i2 < 4; ++i2) {
        int c0 = quad * 8 + i2 * 2, c1 = c0 + 1;
        float a0, a1;
        if (l == 0) {
            a0 = (c0 < 18) ? Wg0[(k * 16 + o) * 18 + c0] * s1 : 0.f;
            a1 = (c1 < 18) ? Wg0[(k * 16 + o) * 18 + c1] * s1 : 0.f;
        } else {
            a0 = (c0 < 16) ? Wgx[(((l - 1) * 7 + k) * 16 + o) * 16 + c0] * s1 : 0.f;
            a1 = (c1 < 16) ? Wgx[(((l - 1) * 7 + k) * 16 + o) * 16 + c1] * s1 : 0.f;
        }
        float t0 = (c0 < 16) ? Wt[(lk * 16 + o) * 16 + c0] * s2 : 0.f;
        float t1 = (c1 < 16) ? Wt[(lk * 16 + o) * 16 + c1] * s2 : 0.f;
        wg4[i2] = pkbf2(a0, a1);
        wt4[i2] = pkbf2(t0, t1);
    }
    *(uint4*)&wgF[(lk * 64 + lane) * 8] = make_uint4(wg4[0], wg4[1], wg4[2], wg4[3]);
    *(uint4*)&wtF[(lk * 64 + lane) * 8] = make_uint4(wt4[0], wt4[1], wt4[2], wt4[3]);
    if (quad == 0)
        bgvA[lk * 16 + o] = ((l == 0) ? bg0[k * 16 + o] : bgx[((l - 1) * 7 + k) * 16 + o]) * s1;
    if (lk == 0 && lane < 48) {
        int ll = lane >> 4, ch = lane & 15;
        float s = 0.f;
        for (int kk = 0; kk < 7; ++kk) {
            int q = (ll * 7 + kk) * 16 + ch;
            s += bt[q] * (g2[q] * rs) + b2[q];
        }
        SbA[ll * 16 + ch] = s;
    }
    if (lk < 4) {   // Asp MFMA frags + row16 -> ws
        ush* aspF = (ush*)((char*)ws + WS_ASP);
        ush* r16F = (ush*)((char*)ws + WS_R16);
        bf16x8 a0 = {};
        #pragma unroll
        for (int i = 0; i < 8; ++i) {
            int v = quad * 8 + i;
            a0[i] = (short)((v < 17) ? f2bf(Asp[(lk * 17 + o) * 17 + v]) : 0);
        }
        *(bf16x8*)&aspF[(lk * 64 + lane) * 8] = a0;
        if (lane < 32)
            r16F[lk * 32 + lane] = (lane < 17) ? f2bf(Asp[(lk * 17 + 16) * 17 + lane]) : (ush)0;
    }
}

// ---------------- transpose-in: x (n,pc,hw) f32 -> xT[site][pc] bf16 ----------------
__global__ __launch_bounds__(256) void stgcn_tin(const float* __restrict__ x,
                                                 void* __restrict__ ws)
{
    __shared__ float tf[32][256];
    const int b = blockIdx.x, tid = threadIdx.x;
    const int n = b & 7, pc0 = (b >> 3) * 32;
    for (int j = 0; j < 32; ++j) {
        int pc = pc0 + j;
        tf[j][tid] = (pc < PC) ? x[((size_t)n * PC + pc) * 256 + tid] : 0.f;
    }
    __syncthreads();
    ush* dst = (ush*)((char*)ws + WS_XT) + (size_t)(n * 256 + tid) * PCP + pc0;
    unsigned pk[16];
    #pragma unroll
    for (int j2 = 0; j2 < 16; ++j2) pk[j2] = pkbf2(tf[2 * j2][tid], tf[2 * j2 + 1][tid]);
    #pragma unroll
    for (int q4 = 0; q4 < 4; ++q4)
        *(uint4*)&dst[q4 * 8] = make_uint4(pk[q4*4], pk[q4*4+1], pk[q4*4+2], pk[q4*4+3]);
}

// ---------------- transpose-out (bf16 outS overlaid on xT rows) ----------------
__global__ __launch_bounds__(256) void stgcn_tout_bf(const void* __restrict__ ws,
                                                     float* __restrict__ out)
{
    __shared__ ush tg[32][256];
    const int b = blockIdx.x, tid = threadIdx.x;
    const int n = b & 7, q0 = (b >> 3) * 32;
    const ush* src = (const ush*)((const char*)ws + WS_XT) + (size_t)(n * 256 + tid) * PCP + q0;
    #pragma unroll
    for (int j4 = 0; j4 < 4; ++j4) {
        uint4 v = *(const uint4*)&src[j4 * 8];
        unsigned u[4] = {v.x, v.y, v.z, v.w};
        #pragma unroll
        for (int e = 0; e < 4; ++e) {
            tg[j4*8 + e*2 + 0][tid] = (ush)(u[e] & 0xffffu);
            tg[j4*8 + e*2 + 1][tid] = (ush)(u[e] >> 16);
        }
    }
    __syncthreads();
    for (int j = 0; j < 32; ++j)
        out[((size_t)n * QN + q0 + j) * 256 + tid] = bf2f(tg[j][tid]);
}

// ---------------- main fused 3-layer kernel, one block per (n,hw) ----------------
// TP: 1 = read bf16 xT from ws and write bf16 outS over own xT row. 0 = direct global I/O.
// (256,4): 4 blocks/CU (42% occupancy). Allocator targets 64 arch-VGPRs and spills
// ~28 regs (absorbed by L1/L2; measured best overall: 204 us main, r15/r16).
template<int TP>
__global__ __launch_bounds__(256, 4) void stgcn_main(
    const float* __restrict__ x,
    const float* __restrict__ Asp_g, const float* __restrict__ Atm_g, const float* __restrict__ Avw_g,
    const float* __restrict__ b1, void* __restrict__ ws,
    float* __restrict__ out)
{
    __shared__ __align__(16) ush xsb[2 * SLX];      // 12832 B  x channels 0-15
    __shared__ __align__(16) ush xs2[NSLOT * 2];    //  1600 B  x channels 16-17 (layer 0)
    __shared__ __align__(16) ush z1g[16 * RS1];     // 13184 B  [o][slot]
    __shared__ __align__(16) ush z2s[2 * SL8];      // 12800 B  [c>>3][slot][c&7]

    const int tid  = threadIdx.x;
    const int wv   = tid >> 6;
    const int lane = tid & 63;
    const int o    = tid & 15;
    const int quad = (tid >> 4) & 3;
    const int w16  = tid >> 4;
    const int bid  = blockIdx.x;
    const int n = bid & 7, hw = bid >> 3;   // XCD swizzle: one batch image per XCD

    const float* bgvA = (const float*)ws;
    const float* SbA  = bgvA + WS_SB_F;
    const ush* wgF  = (const ush*)((const char*)ws + WS_WG);
    const ush* wtF  = (const ush*)((const char*)ws + WS_WT);
    const ush* aspF = (const ush*)((const char*)ws + WS_ASP);
    const ush* r16F = (const ush*)((const char*)ws + WS_R16);

    // zero LDS (pads/tails must be finite-zero)
    for (int i = tid; i < SLX; i += 256) ((unsigned*)xsb)[i] = 0u;
    for (int i = tid; i < NSLOT; i += 256) ((unsigned*)xs2)[i] = 0u;
    for (int i = tid; i < (16 * RS1) / 2; i += 256) ((unsigned*)z1g)[i] = 0u;
    for (int i = tid; i < SL8; i += 256) ((unsigned*)z2s)[i] = 0u;
    __syncthreads();

    // load x -> bf16 LDS (slot-padded subtiled layout; ch 16-17 compact)
    if (TP) {
        const ush* xrow = (const ush*)((const char*)ws + WS_XT) + (size_t)(n * 256 + hw) * PCP;
        for (int i = tid; i < PC; i += 256) {
            int p = i / CIN, c = i - p * CIN;
            int slot = p + 3 * (p / 17);
            if (c < 16) xsb[(c >> 3) * SLX + slot * 8 + (c & 7)] = xrow[i];
            else        xs2[slot * 2 + (c - 16)] = xrow[i];
        }
    } else {
        const float* xb = x + (size_t)n * PC * 256 + hw;
        for (int i = tid; i < PC; i += 256) {
            int p = i / CIN, c = i - p * CIN;
            int slot = p + 3 * (p / 17);
            ush v = f2bf(xb[(size_t)i * 256]);
            if (c < 16) xsb[(c >> 3) * SLX + slot * 8 + (c & 7)] = v;
            else        xs2[slot * 2 + (c - 16)] = v;
        }
    }
    __syncthreads();

    f32x4 acc[7];

    #pragma unroll 1
    for (int l = 0; l < 3; ++l) {
        // init acc: residual = 7*x (re-read bf16 from xsb; branches see the same values)
        #pragma unroll
        for (int t = 0; t < 7; ++t) {
            int tile = t * 4 + wv;
            f32x4 z = {0.f, 0.f, 0.f, 0.f};
            acc[t] = z;
            if (l > 0 && tile < NTILE) {
                int node = tile * 16 + o;
                uint2 w = *(const uint2*)&xsb[(quad >> 1) * SLX + node * 8 + (quad & 1) * 4];
                acc[t][0] = 7.f * bf2f((ush)(w.x & 0xffffu));
                acc[t][1] = 7.f * bf2f((ush)(w.x >> 16));
                acc[t][2] = 7.f * bf2f((ush)(w.y & 0xffffu));
                acc[t][3] = 7.f * bf2f((ush)(w.y >> 16));
            }
        }

        #pragma unroll 1   // rolled: small body, low register pressure
        for (int k = 0; k < 7; ++k) {
            const int lk = l * 7 + k;
            bf16x8 wg = *(const bf16x8*)&wgF[(lk * 64 + lane) * 8];
            bf16x8 wt = *(const bf16x8*)&wtF[(lk * 64 + lane) * 8];
            const float bgv = bgvA[lk * 16 + o];

            // ---- conv1: z1[o][slot] via MFMA (bias in C-operand) ----
            // quads 0,1 carry ch 0-15; quad 2 only layer-0 ch 16,17; quad 3 zero.
            #pragma unroll
            for (int t = 0; t < 7; ++t) {
                int tile = t * 4 + wv;
                if (tile < NTILE) {
                    int node = tile * 16 + o;
                    bf16x8 xa = {};
                    if (quad < 2) {
                        xa = *(const bf16x8*)&xsb[quad * SLX + node * 8];
                    } else if (quad == 2 && l == 0) {
                        unsigned w2 = *(const unsigned*)&xs2[node * 2];
                        xa[0] = (short)(ush)(w2 & 0xffffu);
                        xa[1] = (short)(ush)(w2 >> 16);
                    }
                    f32x4 z = {bgv, bgv, bgv, bgv};
                    z = __builtin_amdgcn_mfma_f32_16x16x32_bf16(xa, wg, z, 0, 0, 0);
                    *(uint2*)&z1g[o * RS1 + tile * 16 + quad * 4] =
                        make_uint2(pkbf2(z[0], z[1]), pkbf2(z[2], z[3]));
                }
            }
            __syncthreads();

            // ---- aggregation -> z2s [c>>3][slot][c&7] ----
            if (k < 4) {   // V-mix, transposed MFMA: lane holds 4 channels of node u=o
                bf16x8 aA = *(const bf16x8*)&aspF[(k * 64 + lane) * 8];
                bf16x8 aB = {};
                if (o == 0) aB = *(const bf16x8*)&r16F[k * 32 + quad * 8];
                float4 b1q = *(const float4*)&b1[lk * 16 + quad * 4];
                #pragma unroll
                for (int gi = 0; gi < 5; ++gi) {
                    int grp = gi * 4 + wv;   // 0..19, all valid
                    bf16x8 bz = *(const bf16x8*)&z1g[o * RS1 + grp * GRP + quad * 8];
                    f32x4 y0 = {b1q.x, b1q.y, b1q.z, b1q.w};
                    y0 = __builtin_amdgcn_mfma_f32_16x16x32_bf16(bz, aA, y0, 0, 0, 0);
                    f32x4 y1 = {b1q.x, b1q.y, b1q.z, b1q.w};
                    y1 = __builtin_amdgcn_mfma_f32_16x16x32_bf16(bz, aB, y1, 0, 0, 0);
                    *(uint2*)&z2s[(quad >> 1) * SL8 + (grp * GRP + o) * 8 + (quad & 1) * 4] =
                        make_uint2(pkbf2(fmaxf(y0[0], 0.f), fmaxf(y0[1], 0.f)),
                                   pkbf2(fmaxf(y0[2], 0.f), fmaxf(y0[3], 0.f)));
                    if (o == 0) {
                        *(uint2*)&z2s[(quad >> 1) * SL8 + (grp * GRP + 16) * 8 + (quad & 1) * 4] =
                            make_uint2(pkbf2(fmaxf(y1[0], 0.f), fmaxf(y1[1], 0.f)),
                                       pkbf2(fmaxf(y1[2], 0.f), fmaxf(y1[3], 0.f)));
                    }
                }
            } else if (k < 6) {   // T-mix (K=5), per-group VALU
                const float b1v = b1[lk * 16 + o];
                const float* Ar = Atm_g + (k - 4) * 25;
                #pragma unroll
                for (int j = 0; j < 5; ++j) {
                    int g = w16 + 16 * j;
                    if (g < 68) {
                        int vw = g / 17, v = g - vw * 17;
                        float vals[5];
                        #pragma unroll
                        for (int t2 = 0; t2 < 5; ++t2)
                            vals[t2] = bf2f(z1g[o * RS1 + vw * 100 + t2 * GRP + v]);
                        #pragma unroll
                        for (int tp = 0; tp < 5; ++tp) {
                            float y = b1v;
                            #pragma unroll
                            for (int t2 = 0; t2 < 5; ++t2)
                                y = fmaf(Ar[tp * 5 + t2], vals[t2], y);
                            z2s[(o >> 3) * SL8 + ((vw * 5 + tp) * GRP + v) * 8 + (o & 7)] =
                                f2bf(fmaxf(y, 0.f));
                        }
                    }
                }
            } else {   // View-mix (K=4), per-group VALU
                const float b1v = b1[lk * 16 + o];
                #pragma unroll
                for (int j = 0; j < 6; ++j) {
                    int g = w16 + 16 * j;
                    if (g < 85) {
                        int tt = g / 17, v = g - tt * 17;
                        float vals[4];
                        #pragma unroll
                        for (int vw = 0; vw < 4; ++vw)
                            vals[vw] = bf2f(z1g[o * RS1 + vw * 100 + tt * GRP + v]);
                        #pragma unroll
                        for (int vp = 0; vp < 4; ++vp) {
                            float y = b1v;
                            #pragma unroll
                            for (int vw = 0; vw < 4; ++vw)
                                y = fmaf(Avw_g[vp * 4 + vw], vals[vw], y);
                            z2s[(o >> 3) * SL8 + ((vp * 5 + tt) * GRP + v) * 8 + (o & 7)] =
                                f2bf(fmaxf(y, 0.f));
                        }
                    }
                }
            }
            __syncthreads();

            // ---- conv2 (transposed): acc[t] holds 4 channels of node tile*16+o ----
            // quads 0,1 carry ch 0-15; quads 2,3 operand zero (wt already zero there).
            #pragma unroll
            for (int t = 0; t < 7; ++t) {
                int tile = t * 4 + wv;
                if (tile < NTILE) {
                    int node = tile * 16 + o;
                    bf16x8 za = {};
                    if (quad < 2) za = *(const bf16x8*)&z2s[quad * SL8 + node * 8];
                    acc[t] = __builtin_amdgcn_mfma_f32_16x16x32_bf16(wt, za, acc[t], 0, 0, 0);
                }
            }
            // no barrier: next conv1 writes z1g only; barrier after it orders z2s reuse
        }

        // ---- finalize layer ----
        float4 Sb4 = *(const float4*)&SbA[l * 16 + quad * 4];
        if (l < 2) {
            __syncthreads();   // all conv1 xsb reads done before overwrite
            #pragma unroll
            for (int t = 0; t < 7; ++t) {
                int tile = t * 4 + wv;
                if (tile < NTILE) {
                    float v0 = fmaxf(acc[t][0] + Sb4.x, 0.f);
                    float v1 = fmaxf(acc[t][1] + Sb4.y, 0.f);
                    float v2 = fmaxf(acc[t][2] + Sb4.z, 0.f);
                    float v3 = fmaxf(acc[t][3] + Sb4.w, 0.f);
                    int s = tile * 16 + o;
                    *(uint2*)&xsb[(quad >> 1) * SLX + s * 8 + (quad & 1) * 4] =
                        make_uint2(pkbf2(v0, v1), pkbf2(v2, v3));
                }
            }
            __syncthreads();
        } else {
            #pragma unroll
            for (int t = 0; t < 7; ++t) {
                int tile = t * 4 + wv;
                if (tile < NTILE) {
                    int s = tile * 16 + o;
                    int m = s / GRP, vv = s - GRP * m;
                    if (vv < 17) {
                        int p = m * 17 + vv;
                        float r0 = fmaxf(acc[t][0] + Sb4.x, 0.f);
                        float r1 = fmaxf(acc[t][1] + Sb4.y, 0.f);
                        float r2 = fmaxf(acc[t][2] + Sb4.z, 0.f);
                        float r3 = fmaxf(acc[t][3] + Sb4.w, 0.f);
                        if (TP) {
                            ush* osrow = (ush*)((char*)ws + WS_XT) + (size_t)(n * 256 + hw) * PCP;
                            *(uint2*)&osrow[p * 16 + quad * 4] =
                                make_uint2(pkbf2(r0, r1), pkbf2(r2, r3));
                        } else {
                            float* ob = out + ((size_t)((n * NODESV + p) * 16 + quad * 4)) * 256 + hw;
                            ob[0] = r0; ob[256] = r1; ob[512] = r2; ob[768] = r3;
                        }
                    }
                }
            }
        }
    }
}

extern "C" void kernel_launch(void* const* d_in, const int* in_sizes, int n_in,
                              void* d_out, int out_size, void* d_ws, size_t ws_size,
                              hipStream_t stream) {
    const float* x    = (const float*)d_in[0];
    const float* Asp  = (const float*)d_in[1];
    const float* Atm  = (const float*)d_in[2];
    const float* Avw  = (const float*)d_in[3];
    const float* Wg0  = (const float*)d_in[4];
    const float* bg0  = (const float*)d_in[5];
    const float* Wgx  = (const float*)d_in[6];
    const float* bgx  = (const float*)d_in[7];
    const float* g1   = (const float*)d_in[8];
    const float* b1   = (const float*)d_in[9];
    const float* Wt   = (const float*)d_in[10];
    const float* bt   = (const float*)d_in[11];
    const float* g2   = (const float*)d_in[12];
    const float* b2   = (const float*)d_in[13];
    float* out = (float*)d_out;

    stgcn_prep<<<dim3(21), dim3(64), 0, stream>>>(
        Asp, Wg0, bg0, Wgx, bgx, g1, b1, Wt, bt, g2, b2, d_ws);

    if (ws_size >= WS_NEED) {
        stgcn_tin<<<dim3(8 * 192), dim3(256), 0, stream>>>(x, d_ws);
        stgcn_main<1><<<dim3(8 * 256), dim3(256), 0, stream>>>(
            x, Asp, Atm, Avw, b1, d_ws, out);
        stgcn_tout_bf<<<dim3(8 * 170), dim3(256), 0, stream>>>(d_ws, out);
    } else {
        stgcn_main<0><<<dim3(8 * 256), dim3(256), 0, stream>>>(
            x, Asp, Atm, Avw, b1, d_ws, out);
    }
}

// Round 19
// 218.265 us; speedup vs baseline: 1.1850x; 1.0827x over previous
//
#include <hip/hip_runtime.h>
#include <hip/hip_bf16.h>

typedef __attribute__((ext_vector_type(8))) short bf16x8;
typedef __attribute__((ext_vector_type(4))) float f32x4;
typedef unsigned short ush;

constexpr int NODESV = 340, CIN = 18;
constexpr int GRP = 20;     // padded group stride (17 valid + 3 pad)
constexpr int NSLOT = 400;  // 20 groups * 20
constexpr int NTILE = 25;   // 400/16
constexpr int RS1 = 412;    // z1g row stride (16-bank spread, covers quad3 overread)
constexpr int SLX = 3208;   // xsb slice stride
constexpr int SL8 = 3200;   // z2s slice stride
constexpr int PC = 6120;    // 340*18
constexpr int PCP = 6144;   // padded xT row (ush); bf16 outS row (5440) overlays it
constexpr int QN = 5440;    // 340*16

// d_ws layout (bytes)
constexpr int    WS_SB_F  = 21 * 16;                     // SbA float offset after bgvA
constexpr int    WS_WG    = 1536;
constexpr int    WS_WT    = WS_WG + 21 * 64 * 8 * 2;     // 23040
constexpr int    WS_ASP   = WS_WT + 21 * 64 * 8 * 2;     // 44544: Asp frags [4][64][8] bf16
constexpr int    WS_R16   = WS_ASP + 4096;               // 48640: row-16 [4][32] bf16
constexpr size_t WS_XT    = 65536;
constexpr size_t WS_NEED  = WS_XT + (size_t)8 * 256 * PCP * 2;   // 25,231,360

__device__ __forceinline__ ush f2bf(float f) {
    union { __hip_bfloat16 h; ush u; } c; c.h = __float2bfloat16(f); return c.u;
}
__device__ __forceinline__ float bf2f(ush s) {
    return __uint_as_float((unsigned)s << 16);
}
__device__ __forceinline__ unsigned pkbf2(float lo, float hi) {
    union { __hip_bfloat162 h; unsigned u; } c;
    c.h = __float22bfloat162_rn(make_float2(lo, hi));
    return c.u;
}

// ---------------- prep: fold BN into bf16 weight frags + Asp frags, once ----------------
__global__ void stgcn_prep(
    const float* __restrict__ Asp,
    const float* __restrict__ Wg0, const float* __restrict__ bg0,
    const float* __restrict__ Wgx, const float* __restrict__ bgx,
    const float* __restrict__ g1,  const float* __restrict__ b1,
    const float* __restrict__ Wt,  const float* __restrict__ bt,
    const float* __restrict__ g2,  const float* __restrict__ b2,
    void* __restrict__ ws)
{
    const int lk = blockIdx.x;            // 0..20
    const int l = lk / 7, k = lk % 7;
    const int lane = threadIdx.x;         // 0..63
    const int o = lane & 15, quad = lane >> 4;
    float* bgvA = (float*)ws;
    float* SbA  = bgvA + WS_SB_F;
    ush* wgF = (ush*)((char*)ws + WS_WG);
    ush* wtF = (ush*)((char*)ws + WS_WT);
    const float rs = 1.0f / sqrtf(1.0f + 1e-5f);
    const float s1 = g1[lk * 16 + o] * rs;
    const float s2 = g2[lk * 16 + o] * rs;

    unsigned wg4[4], wt4[4];
    #pragma unroll
    for (int i2 = 0; i2 < 4; ++i2) {
        int c0 = quad * 8 + i2 * 2, c1 = c0 + 1;
        float a0, a1;
        if (l == 0) {
            a0 = (c0 < 18) ? Wg0[(k * 16 + o) * 18 + c0] * s1 : 0.f;
            a1 = (c1 < 18) ? Wg0[(k * 16 + o) * 18 + c1] * s1 : 0.f;
        } else {
            a0 = (c0 < 16) ? Wgx[(((l - 1) * 7 + k) * 16 + o) * 16 + c0] * s1 : 0.f;
            a1 = (c1 < 16) ? Wgx[(((l - 1) * 7 + k) * 16 + o) * 16 + c1] * s1 : 0.f;
        }
        float t0 = (c0 < 16) ? Wt[(lk * 16 + o) * 16 + c0] * s2 : 0.f;
        float t1 = (c1 < 16) ? Wt[(lk * 16 + o) * 16 + c1] * s2 : 0.f;
        wg4[i2] = pkbf2(a0, a1);
        wt4[i2] = pkbf2(t0, t1);
    }
    *(uint4*)&wgF[(lk * 64 + lane) * 8] = make_uint4(wg4[0], wg4[1], wg4[2], wg4[3]);
    *(uint4*)&wtF[(lk * 64 + lane) * 8] = make_uint4(wt4[0], wt4[1], wt4[2], wt4[3]);
    if (quad == 0)
        bgvA[lk * 16 + o] = ((l == 0) ? bg0[k * 16 + o] : bgx[((l - 1) * 7 + k) * 16 + o]) * s1;
    if (lk == 0 && lane < 48) {
        int ll = lane >> 4, ch = lane & 15;
        float s = 0.f;
        for (int kk = 0; kk < 7; ++kk) {
            int q = (ll * 7 + kk) * 16 + ch;
            s += bt[q] * (g2[q] * rs) + b2[q];
        }
        SbA[ll * 16 + ch] = s;
    }
    if (lk < 4) {   // Asp MFMA frags + row16 -> ws
        ush* aspF = (ush*)((char*)ws + WS_ASP);
        ush* r16F = (ush*)((char*)ws + WS_R16);
        bf16x8 a0 = {};
        #pragma unroll
        for (int i = 0; i < 8; ++i) {
            int v = quad * 8 + i;
            a0[i] = (short)((v < 17) ? f2bf(Asp[(lk * 17 + o) * 17 + v]) : 0);
        }
        *(bf16x8*)&aspF[(lk * 64 + lane) * 8] = a0;
        if (lane < 32)
            r16F[lk * 32 + lane] = (lane < 17) ? f2bf(Asp[(lk * 17 + 16) * 17 + lane]) : (ush)0;
    }
}

// ---------------- transpose-in: x (n,pc,hw) f32 -> xT[site][pc] bf16 ----------------
__global__ __launch_bounds__(256) void stgcn_tin(const float* __restrict__ x,
                                                 void* __restrict__ ws)
{
    __shared__ float tf[32][256];
    const int b = blockIdx.x, tid = threadIdx.x;
    const int n = b & 7, pc0 = (b >> 3) * 32;
    for (int j = 0; j < 32; ++j) {
        int pc = pc0 + j;
        tf[j][tid] = (pc < PC) ? x[((size_t)n * PC + pc) * 256 + tid] : 0.f;
    }
    __syncthreads();
    ush* dst = (ush*)((char*)ws + WS_XT) + (size_t)(n * 256 + tid) * PCP + pc0;
    unsigned pk[16];
    #pragma unroll
    for (int j2 = 0; j2 < 16; ++j2) pk[j2] = pkbf2(tf[2 * j2][tid], tf[2 * j2 + 1][tid]);
    #pragma unroll
    for (int q4 = 0; q4 < 4; ++q4)
        *(uint4*)&dst[q4 * 8] = make_uint4(pk[q4*4], pk[q4*4+1], pk[q4*4+2], pk[q4*4+3]);
}

// ---------------- transpose-out (bf16 outS overlaid on xT rows) ----------------
__global__ __launch_bounds__(256) void stgcn_tout_bf(const void* __restrict__ ws,
                                                     float* __restrict__ out)
{
    __shared__ ush tg[32][256];
    const int b = blockIdx.x, tid = threadIdx.x;
    const int n = b & 7, q0 = (b >> 3) * 32;
    const ush* src = (const ush*)((const char*)ws + WS_XT) + (size_t)(n * 256 + tid) * PCP + q0;
    #pragma unroll
    for (int j4 = 0; j4 < 4; ++j4) {
        uint4 v = *(const uint4*)&src[j4 * 8];
        unsigned u[4] = {v.x, v.y, v.z, v.w};
        #pragma unroll
        for (int e = 0; e < 4; ++e) {
            tg[j4*8 + e*2 + 0][tid] = (ush)(u[e] & 0xffffu);
            tg[j4*8 + e*2 + 1][tid] = (ush)(u[e] >> 16);
        }
    }
    __syncthreads();
    for (int j = 0; j < 32; ++j)
        out[((size_t)n * QN + q0 + j) * 256 + tid] = bf2f(tg[j][tid]);
}

// ---------------- main fused 3-layer kernel, one 512-thread block per (n,hw) ----------------
// TP: 1 = read bf16 xT from ws and write bf16 outS over own xT row. 0 = direct global I/O.
// 512 threads (8 waves, ~3 tiles/wave -> acc[4]=16 regs, peak demand ~60).
// (512,2): 2 blocks/CU = 16 waves/CU = 4 waves/EU (same 42% occupancy as r15/r18);
// allocator 2x-target = 8 waves/EU -> cap 64 >= demand -> SPILL-FREE at 4-wave occupancy.
template<int TP>
__global__ __launch_bounds__(512, 2) void stgcn_main(
    const float* __restrict__ x,
    const float* __restrict__ Asp_g, const float* __restrict__ Atm_g, const float* __restrict__ Avw_g,
    const float* __restrict__ b1, void* __restrict__ ws,
    float* __restrict__ out)
{
    __shared__ __align__(16) ush xsb[2 * SLX];      // 12832 B  x channels 0-15
    __shared__ __align__(16) ush xs2[NSLOT * 2];    //  1600 B  x channels 16-17 (layer 0)
    __shared__ __align__(16) ush z1g[16 * RS1];     // 13184 B  [o][slot]
    __shared__ __align__(16) ush z2s[2 * SL8];      // 12800 B  [c>>3][slot][c&7]

    const int tid  = threadIdx.x;
    const int wv   = tid >> 6;          // 0..7
    const int lane = tid & 63;
    const int o    = tid & 15;
    const int quad = (tid >> 4) & 3;
    const int w16  = tid >> 4;          // 0..31
    const int bid  = blockIdx.x;
    const int n = bid & 7, hw = bid >> 3;   // XCD swizzle: one batch image per XCD

    const float* bgvA = (const float*)ws;
    const float* SbA  = bgvA + WS_SB_F;
    const ush* wgF  = (const ush*)((const char*)ws + WS_WG);
    const ush* wtF  = (const ush*)((const char*)ws + WS_WT);
    const ush* aspF = (const ush*)((const char*)ws + WS_ASP);
    const ush* r16F = (const ush*)((const char*)ws + WS_R16);

    // zero LDS (pads/tails must be finite-zero)
    for (int i = tid; i < SLX; i += 512) ((unsigned*)xsb)[i] = 0u;
    for (int i = tid; i < NSLOT; i += 512) ((unsigned*)xs2)[i] = 0u;
    for (int i = tid; i < (16 * RS1) / 2; i += 512) ((unsigned*)z1g)[i] = 0u;
    for (int i = tid; i < SL8; i += 512) ((unsigned*)z2s)[i] = 0u;
    __syncthreads();

    // load x -> bf16 LDS (slot-padded subtiled layout; ch 16-17 compact)
    if (TP) {
        const ush* xrow = (const ush*)((const char*)ws + WS_XT) + (size_t)(n * 256 + hw) * PCP;
        for (int i = tid; i < PC; i += 512) {
            int p = i / CIN, c = i - p * CIN;
            int slot = p + 3 * (p / 17);
            if (c < 16) xsb[(c >> 3) * SLX + slot * 8 + (c & 7)] = xrow[i];
            else        xs2[slot * 2 + (c - 16)] = xrow[i];
        }
    } else {
        const float* xb = x + (size_t)n * PC * 256 + hw;
        for (int i = tid; i < PC; i += 512) {
            int p = i / CIN, c = i - p * CIN;
            int slot = p + 3 * (p / 17);
            ush v = f2bf(xb[(size_t)i * 256]);
            if (c < 16) xsb[(c >> 3) * SLX + slot * 8 + (c & 7)] = v;
            else        xs2[slot * 2 + (c - 16)] = v;
        }
    }
    __syncthreads();

    f32x4 acc[4];

    #pragma unroll 1
    for (int l = 0; l < 3; ++l) {
        // init acc: residual = 7*x (re-read bf16 from xsb; branches see the same values)
        #pragma unroll
        for (int t = 0; t < 4; ++t) {
            int tile = t * 8 + wv;
            f32x4 z = {0.f, 0.f, 0.f, 0.f};
            acc[t] = z;
            if (l > 0 && tile < NTILE) {
                int node = tile * 16 + o;
                uint2 w = *(const uint2*)&xsb[(quad >> 1) * SLX + node * 8 + (quad & 1) * 4];
                acc[t][0] = 7.f * bf2f((ush)(w.x & 0xffffu));
                acc[t][1] = 7.f * bf2f((ush)(w.x >> 16));
                acc[t][2] = 7.f * bf2f((ush)(w.y & 0xffffu));
                acc[t][3] = 7.f * bf2f((ush)(w.y >> 16));
            }
        }

        #pragma unroll 1   // rolled: small body, low register pressure
        for (int k = 0; k < 7; ++k) {
            const int lk = l * 7 + k;
            bf16x8 wg = *(const bf16x8*)&wgF[(lk * 64 + lane) * 8];
            bf16x8 wt = *(const bf16x8*)&wtF[(lk * 64 + lane) * 8];
            const float bgv = bgvA[lk * 16 + o];

            // ---- conv1: z1[o][slot] via MFMA (bias in C-operand) ----
            // quads 0,1 carry ch 0-15; quad 2 only layer-0 ch 16,17; quad 3 zero.
            #pragma unroll
            for (int t = 0; t < 4; ++t) {
                int tile = t * 8 + wv;
                if (tile < NTILE) {
                    int node = tile * 16 + o;
                    bf16x8 xa = {};
                    if (quad < 2) {
                        xa = *(const bf16x8*)&xsb[quad * SLX + node * 8];
                    } else if (quad == 2 && l == 0) {
                        unsigned w2 = *(const unsigned*)&xs2[node * 2];
                        xa[0] = (short)(ush)(w2 & 0xffffu);
                        xa[1] = (short)(ush)(w2 >> 16);
                    }
                    f32x4 z = {bgv, bgv, bgv, bgv};
                    z = __builtin_amdgcn_mfma_f32_16x16x32_bf16(xa, wg, z, 0, 0, 0);
                    *(uint2*)&z1g[o * RS1 + tile * 16 + quad * 4] =
                        make_uint2(pkbf2(z[0], z[1]), pkbf2(z[2], z[3]));
                }
            }
            __syncthreads();

            // ---- aggregation -> z2s [c>>3][slot][c&7] ----
            if (k < 4) {   // V-mix, transposed MFMA: lane holds 4 channels of node u=o
                bf16x8 aA = *(const bf16x8*)&aspF[(k * 64 + lane) * 8];
                bf16x8 aB = {};
                if (o == 0) aB = *(const bf16x8*)&r16F[k * 32 + quad * 8];
                float4 b1q = *(const float4*)&b1[lk * 16 + quad * 4];
                #pragma unroll
                for (int gi = 0; gi < 3; ++gi) {
                    int grp = gi * 8 + wv;   // 0..23, guard <20
                    if (grp < 20) {
                        bf16x8 bz = *(const bf16x8*)&z1g[o * RS1 + grp * GRP + quad * 8];
                        f32x4 y0 = {b1q.x, b1q.y, b1q.z, b1q.w};
                        y0 = __builtin_amdgcn_mfma_f32_16x16x32_bf16(bz, aA, y0, 0, 0, 0);
                        f32x4 y1 = {b1q.x, b1q.y, b1q.z, b1q.w};
                        y1 = __builtin_amdgcn_mfma_f32_16x16x32_bf16(bz, aB, y1, 0, 0, 0);
                        *(uint2*)&z2s[(quad >> 1) * SL8 + (grp * GRP + o) * 8 + (quad & 1) * 4] =
                            make_uint2(pkbf2(fmaxf(y0[0], 0.f), fmaxf(y0[1], 0.f)),
                                       pkbf2(fmaxf(y0[2], 0.f), fmaxf(y0[3], 0.f)));
                        if (o == 0) {
                            *(uint2*)&z2s[(quad >> 1) * SL8 + (grp * GRP + 16) * 8 + (quad & 1) * 4] =
                                make_uint2(pkbf2(fmaxf(y1[0], 0.f), fmaxf(y1[1], 0.f)),
                                           pkbf2(fmaxf(y1[2], 0.f), fmaxf(y1[3], 0.f)));
                        }
                    }
                }
            } else if (k < 6) {   // T-mix (K=5), per-group VALU
                const float b1v = b1[lk * 16 + o];
                const float* Ar = Atm_g + (k - 4) * 25;
                #pragma unroll
                for (int j = 0; j < 3; ++j) {
                    int g = w16 + 32 * j;
                    if (g < 68) {
                        int vw = g / 17, v = g - vw * 17;
                        float vals[5];
                        #pragma unroll
                        for (int t2 = 0; t2 < 5; ++t2)
                            vals[t2] = bf2f(z1g[o * RS1 + vw * 100 + t2 * GRP + v]);
                        #pragma unroll
                        for (int tp = 0; tp < 5; ++tp) {
                            float y = b1v;
                            #pragma unroll
                            for (int t2 = 0; t2 < 5; ++t2)
                                y = fmaf(Ar[tp * 5 + t2], vals[t2], y);
                            z2s[(o >> 3) * SL8 + ((vw * 5 + tp) * GRP + v) * 8 + (o & 7)] =
                                f2bf(fmaxf(y, 0.f));
                        }
                    }
                }
            } else {   // View-mix (K=4), per-group VALU
                const float b1v = b1[lk * 16 + o];
                #pragma unroll
                for (int j = 0; j < 3; ++j) {
                    int g = w16 + 32 * j;
                    if (g < 85) {
                        int tt = g / 17, v = g - tt * 17;
                        float vals[4];
                        #pragma unroll
                        for (int vw = 0; vw < 4; ++vw)
                            vals[vw] = bf2f(z1g[o * RS1 + vw * 100 + tt * GRP + v]);
                        #pragma unroll
                        for (int vp = 0; vp < 4; ++vp) {
                            float y = b1v;
                            #pragma unroll
                            for (int vw = 0; vw < 4; ++vw)
                                y = fmaf(Avw_g[vp * 4 + vw], vals[vw], y);
                            z2s[(o >> 3) * SL8 + ((vp * 5 + tt) * GRP + v) * 8 + (o & 7)] =
                                f2bf(fmaxf(y, 0.f));
                        }
                    }
                }
            }
            __syncthreads();

            // ---- conv2 (transposed): acc[t] holds 4 channels of node tile*16+o ----
            // quads 0,1 carry ch 0-15; quads 2,3 operand zero (wt already zero there).
            #pragma unroll
            for (int t = 0; t < 4; ++t) {
                int tile = t * 8 + wv;
                if (tile < NTILE) {
                    int node = tile * 16 + o;
                    bf16x8 za = {};
                    if (quad < 2) za = *(const bf16x8*)&z2s[quad * SL8 + node * 8];
                    acc[t] = __builtin_amdgcn_mfma_f32_16x16x32_bf16(wt, za, acc[t], 0, 0, 0);
                }
            }
            // no barrier: next conv1 writes z1g only; barrier after it orders z2s reuse
        }

        // ---- finalize layer ----
        float4 Sb4 = *(const float4*)&SbA[l * 16 + quad * 4];
        if (l < 2) {
            __syncthreads();   // all conv1 xsb reads done before overwrite
            #pragma unroll
            for (int t = 0; t < 4; ++t) {
                int tile = t * 8 + wv;
                if (tile < NTILE) {
                    float v0 = fmaxf(acc[t][0] + Sb4.x, 0.f);
                    float v1 = fmaxf(acc[t][1] + Sb4.y, 0.f);
                    float v2 = fmaxf(acc[t][2] + Sb4.z, 0.f);
                    float v3 = fmaxf(acc[t][3] + Sb4.w, 0.f);
                    int s = tile * 16 + o;
                    *(uint2*)&xsb[(quad >> 1) * SLX + s * 8 + (quad & 1) * 4] =
                        make_uint2(pkbf2(v0, v1), pkbf2(v2, v3));
                }
            }
            __syncthreads();
        } else {
            #pragma unroll
            for (int t = 0; t < 4; ++t) {
                int tile = t * 8 + wv;
                if (tile < NTILE) {
                    int s = tile * 16 + o;
                    int m = s / GRP, vv = s - GRP * m;
                    if (vv < 17) {
                        int p = m * 17 + vv;
                        float r0 = fmaxf(acc[t][0] + Sb4.x, 0.f);
                        float r1 = fmaxf(acc[t][1] + Sb4.y, 0.f);
                        float r2 = fmaxf(acc[t][2] + Sb4.z, 0.f);
                        float r3 = fmaxf(acc[t][3] + Sb4.w, 0.f);
                        if (TP) {
                            ush* osrow = (ush*)((char*)ws + WS_XT) + (size_t)(n * 256 + hw) * PCP;
                            *(uint2*)&osrow[p * 16 + quad * 4] =
                                make_uint2(pkbf2(r0, r1), pkbf2(r2, r3));
                        } else {
                            float* ob = out + ((size_t)((n * NODESV + p) * 16 + quad * 4)) * 256 + hw;
                            ob[0] = r0; ob[256] = r1; ob[512] = r2; ob[768] = r3;
                        }
                    }
                }
            }
        }
    }
}

extern "C" void kernel_launch(void* const* d_in, const int* in_sizes, int n_in,
                              void* d_out, int out_size, void* d_ws, size_t ws_size,
                              hipStream_t stream) {
    const float* x    = (const float*)d_in[0];
    const float* Asp  = (const float*)d_in[1];
    const float* Atm  = (const float*)d_in[2];
    const float* Avw  = (const float*)d_in[3];
    const float* Wg0  = (const float*)d_in[4];
    const float* bg0  = (const float*)d_in[5];
    const float* Wgx  = (const float*)d_in[6];
    const float* bgx  = (const float*)d_in[7];
    const float* g1   = (const float*)d_in[8];
    const float* b1   = (const float*)d_in[9];
    const float* Wt   = (const float*)d_in[10];
    const float* bt   = (const float*)d_in[11];
    const float* g2   = (const float*)d_in[12];
    const float* b2   = (const float*)d_in[13];
    float* out = (float*)d_out;

    stgcn_prep<<<dim3(21), dim3(64), 0, stream>>>(
        Asp, Wg0, bg0, Wgx, bgx, g1, b1, Wt, bt, g2, b2, d_ws);

    if (ws_size >= WS_NEED) {
        stgcn_tin<<<dim3(8 * 192), dim3(256), 0, stream>>>(x, d_ws);
        stgcn_main<1><<<dim3(8 * 256), dim3(512), 0, stream>>>(
            x, Asp, Atm, Avw, b1, d_ws, out);
        stgcn_tout_bf<<<dim3(8 * 170), dim3(256), 0, stream>>>(d_ws, out);
    } else {
        stgcn_main<0><<<dim3(8 * 256), dim3(512), 0, stream>>>(
            x, Asp, Atm, Avw, b1, d_ws, out);
    }
}